// Round 4
// baseline (198.344 us; speedup 1.0000x reference)
//
#include <hip/hip_runtime.h>

// Problem constants: B=2, S=2048, D=1024, H=16, HD=64
#define S_LEN 2048
#define NH 16
#define HD 64
#define DMODEL 1024

typedef __bf16 bf16x8 __attribute__((ext_vector_type(8)));
typedef float floatx4 __attribute__((ext_vector_type(4)));
typedef short short8 __attribute__((ext_vector_type(8)));

__device__ inline unsigned short f2bf(float f) {
    union { float f; unsigned u; } v; v.f = f;
    unsigned u = v.u;
    unsigned r = (u + 0x7FFFu + ((u >> 16) & 1u)) >> 16;  // RNE
    return (unsigned short)r;
}

__device__ __forceinline__ void gload_lds16(const void* g, void* l) {
    __builtin_amdgcn_global_load_lds(
        (const __attribute__((address_space(1))) unsigned int*)g,
        (__attribute__((address_space(3))) unsigned int*)l, 16, 0, 0);
}

// counted-vmcnt barrier: wait only for loads older than the newest N, then
// raw s_barrier. "memory" clobber = compiler-level fence (stops gload/ds_read
// motion across it); sched_barrier pins scheduling (rule #18).
#define WAITV_BAR(N) do { \
    asm volatile("s_waitcnt vmcnt(" #N ")\n\ts_barrier" ::: "memory"); \
    __builtin_amdgcn_sched_barrier(0); \
} while (0)

// ---------------------------------------------------------------------------
// K0: prepass. fp32 -> bf16 for x, w_qkv, w_proj (RNE), and cos/sin table.
// ---------------------------------------------------------------------------
__device__ __forceinline__ void cvt4(const float4* __restrict__ src,
                                     uint2* __restrict__ dst, int i) {
    float4 v = src[i];
    union { unsigned short u[4]; uint2 d; } o;
    o.u[0] = f2bf(v.x); o.u[1] = f2bf(v.y); o.u[2] = f2bf(v.z); o.u[3] = f2bf(v.w);
    dst[i] = o.d;
}

__global__ __launch_bounds__(256) void prep_kernel(
    const float* __restrict__ x, const float* __restrict__ wq,
    const float* __restrict__ wp, const float* __restrict__ freqs,
    unsigned short* __restrict__ xb, unsigned short* __restrict__ wqb,
    unsigned short* __restrict__ wpb, float2* __restrict__ cs)
{
    const int tid = blockIdx.x * 256 + threadIdx.x;
    const int nth = gridDim.x * 256;
    for (int i = tid; i < (4096 * 1024) / 4; i += nth) cvt4((const float4*)x, (uint2*)xb, i);
    for (int i = tid; i < (3072 * 1024) / 4; i += nth) cvt4((const float4*)wq, (uint2*)wqb, i);
    for (int i = tid; i < (1024 * 1024) / 4; i += nth) cvt4((const float4*)wp, (uint2*)wpb, i);
    for (int i = tid; i < S_LEN * 32; i += nth) {
        const float f = freqs[i];
        float2 c; c.x = cosf(f); c.y = sinf(f);
        cs[i] = c;
    }
}

// Bank swizzle for 32-col (4x16B-chunk) row-major LDS tiles.
#define SROW(r) (((r) & 3) ^ (((r) >> 2) & 3))

// ---------------------------------------------------------------------------
// K1: qkv = x_bf16 @ w_qkv_bf16^T + b_qkv, fused RoPE (table) + scatter.
// 128x128 tile, BK=32. NEW: ring-4 LDS buffers, depth-2 prefetch, counted
// vmcnt(8) -> loads stay in flight ACROSS barriers (T4); raw s_barrier,
// ONE barrier per K-step, no full drain in the main loop.
//  q -> [bh][s][hd] row-major, PRE-SCALED by 1/sqrt(HD)=0.125 (exact)
//  k -> blocked [bh][hdblk(8)][s(2048)][8]   (RoPE applied)
//  v -> blocked [bh][sblk(256)][hd(64)][8]   (transposed via LDS tile)
// ---------------------------------------------------------------------------
#define QKV_STAGE(bi, kk) do { \
    unsigned short* dA_ = smem + (bi) * 8192; \
    unsigned short* dB_ = dA_ + 4096; \
    gload_lds16(ag + (kk),               dA_ + wv * 512); \
    gload_lds16(ag + 64 * DMODEL + (kk), dA_ + 2048 + wv * 512); \
    gload_lds16(bg + (kk),               dB_ + wv * 512); \
    gload_lds16(bg + 64 * DMODEL + (kk), dB_ + 2048 + wv * 512); \
} while (0)

#define QKV_COMPUTE(bi) do { \
    const unsigned short* sA_ = smem + (bi) * 8192; \
    const unsigned short* sB_ = sA_ + 4096; \
    bf16x8 af[4]; \
    _Pragma("unroll") for (int m_ = 0; m_ < 4; m_++) af[m_] = *(const bf16x8*)&sA_[aoff[m_]]; \
    _Pragma("unroll") for (int n_ = 0; n_ < 4; n_++) { \
        bf16x8 bf = *(const bf16x8*)&sB_[boff[n_]]; \
        _Pragma("unroll") for (int m_ = 0; m_ < 4; m_++) \
            acc[m_][n_] = __builtin_amdgcn_mfma_f32_16x16x32_bf16(af[m_], bf, acc[m_][n_], 0, 0, 0); \
    } \
} while (0)

__global__ __launch_bounds__(256, 2) void qkv_gemm_kernel(
    const unsigned short* __restrict__ xb, const unsigned short* __restrict__ wqb,
    const float* __restrict__ bias, const float2* __restrict__ cs,
    unsigned short* __restrict__ qb, unsigned short* __restrict__ kb,
    unsigned short* __restrict__ vb)
{
    // ring-4: buffer i at smem + i*8192 (A 4096 shorts, B 4096 shorts) = 64KB.
    // V epilogue reuses smem as 128x72 tile (9216 shorts).
    __shared__ __align__(16) unsigned short smem[32768];

    const int t = threadIdx.x;
    const int v = (blockIdx.x & 7) * 96 + (blockIdx.x >> 3);   // XCD swizzle
    const int mbase = (v / 24) * 128;   // 32 m-tiles
    const int nbase = (v % 24) * 128;   // 24 n-tiles
    const int wv = t >> 6, lane = t & 63;
    const int quad = lane >> 4, l16 = lane & 15;
    const int wr = wv >> 1, wc = wv & 1;

    floatx4 acc[4][4];
    #pragma unroll
    for (int m = 0; m < 4; m++)
        #pragma unroll
        for (int n = 0; n < 4; n++)
            #pragma unroll
            for (int r = 0; r < 4; r++) acc[m][n][r] = 0.f;

    const int srow = t >> 2;
    const int schunk = (t & 3) ^ SROW(srow);
    const unsigned short* ag = xb + (size_t)(mbase + srow) * DMODEL + schunk * 8;
    const unsigned short* bg = wqb + (size_t)(nbase + srow) * DMODEL + schunk * 8;

    const int Sl = SROW(l16);
    int aoff[4], boff[4];
    #pragma unroll
    for (int m = 0; m < 4; m++) aoff[m] = (wr * 64 + m * 16 + l16) * 32 + (quad ^ Sl) * 8;
    #pragma unroll
    for (int n = 0; n < 4; n++) boff[n] = (wc * 64 + n * 16 + l16) * 32 + (quad ^ Sl) * 8;

    // Ring invariant entering iter t: STAGE(t-1) retired; {t, t+1} in flight.
    // Iter t: issue STAGE(t+2); vmcnt(8) -> t landed, {t+1, t+2} stay in
    // flight across the barrier; barrier; compute t.
    // Buf b re-issued at iter b+2, program-ordered after barrier(b+1) which
    // all waves pass only after consuming buf b (lgkmcnt-gated MFMAs).
    QKV_STAGE(0, 0);
    QKV_STAGE(1, 32);
    #pragma unroll 4
    for (int tt = 0; tt < 28; tt++) {
        QKV_STAGE((tt + 2) & 3, (tt + 2) * 32);
        WAITV_BAR(8);
        QKV_COMPUTE(tt & 3);
    }
    QKV_STAGE(2, 30 * 32); WAITV_BAR(8); QKV_COMPUTE(0);   // t=28
    QKV_STAGE(3, 31 * 32); WAITV_BAR(8); QKV_COMPUTE(1);   // t=29
    WAITV_BAR(4); QKV_COMPUTE(2);                           // t=30
    WAITV_BAR(0); QKV_COMPUTE(3);                           // t=31

    const int part = nbase >> 10;                 // 0=q 1=k 2=v
    const int bidx = mbase >> 11;
    const int s0   = mbase & 2047;

    if (part == 2) {
        unsigned short* Vt = smem;                // 128 hd x 72 s-pad
        const int hb = (nbase & 1023) >> 6;
        float bvv[4];
        #pragma unroll
        for (int nt = 0; nt < 4; nt++) bvv[nt] = bias[nbase + wc * 64 + nt * 16 + l16];
        #pragma unroll
        for (int shalf = 0; shalf < 2; shalf++) {
            __syncthreads();
            if (wr == shalf) {
                #pragma unroll
                for (int nt = 0; nt < 4; nt++) {
                    const int hdl = wc * 64 + nt * 16 + l16;
                    #pragma unroll
                    for (int m = 0; m < 4; m++)
                        #pragma unroll
                        for (int r = 0; r < 4; r++)
                            Vt[hdl * 72 + m * 16 + quad * 4 + r] = f2bf(acc[m][nt][r] + bvv[nt]);
                }
            }
            __syncthreads();
            const int hdl = t & 127, sp = t >> 7;
            const size_t bh2 = (size_t)bidx * NH + hb + (hdl >> 6);
            #pragma unroll
            for (int c = 0; c < 4; c++) {
                const int sl0 = (sp * 4 + c) * 8;
                const int sg = s0 + shalf * 64 + sl0;
                short8 vv = *(const short8*)&Vt[hdl * 72 + sl0];
                *(short8*)&vb[((bh2 * 256 + (sg >> 3)) * 64 + (hdl & 63)) * 8] = vv;
            }
        }
    } else {
        const size_t bhb = (size_t)bidx * NH;
        const int odd = l16 & 1;
        #pragma unroll
        for (int nt = 0; nt < 4; nt++) {
            const int n_ = nbase + wc * 64 + nt * 16 + l16;
            const int hd = n_ & 63;
            const size_t bh = bhb + ((n_ & 1023) >> 6);
            const float bvv = bias[n_];
            const int ci = (nt * 16 + l16) >> 1;
            #pragma unroll
            for (int m = 0; m < 4; m++) {
                #pragma unroll
                for (int r = 0; r < 4; r++) {
                    const int s = s0 + wr * 64 + m * 16 + quad * 4 + r;
                    float val = acc[m][nt][r] + bvv;
                    float other = __shfl_xor(val, 1, 64);
                    const float2 csv = cs[(size_t)s * 32 + ci];
                    float outv = odd ? fmaf(other, csv.y, val * csv.x)
                                     : fmaf(-other, csv.y, val * csv.x);
                    if (part == 0) {
                        qb[(bh * S_LEN + s) * HD + hd] = f2bf(outv * 0.125f);
                    } else {
                        kb[((bh * 8 + (hd >> 3)) * (size_t)S_LEN + s) * 8 + (hd & 7)] = f2bf(outv);
                    }
                }
            }
        }
    }
}

// ---------------------------------------------------------------------------
// K2: causal flash attention (unchanged from R3: 2-phase dbuf staging,
// reversed qt launch order).
// ---------------------------------------------------------------------------
__global__ __launch_bounds__(256, 3) void attn_kernel(
    const unsigned short* __restrict__ qb, const unsigned short* __restrict__ kb,
    const unsigned short* __restrict__ vbk, unsigned short* __restrict__ ao)
{
    __shared__ __align__(16) unsigned short Ks[2][8 * 512];
    __shared__ __align__(16) unsigned short Vt[2][8 * 512];
    __shared__ __align__(16) unsigned short Pw[4][16 * 72];

    const int t = threadIdx.x;
    const int wv = t >> 6, lane = t & 63, quad = lane >> 4, l16 = lane & 15;
    const int qt   = 31 - (blockIdx.x >> 5);      // reversed: long blocks first
    const int bhid = blockIdx.x & 31;
    const int h = bhid & 15, b = bhid >> 4;
    const size_t bh = (size_t)b * NH + h;
    const unsigned short* qg  = qb + bh * S_LEN * HD;
    const unsigned short* kgB = kb + bh * 8 * S_LEN * 8;
    const unsigned short* vgB = vbk + bh * 256 * 64 * 8;

    bf16x8 qf[2];
    {
        const unsigned short* q0 = qg + (size_t)(qt * 64 + wv * 16 + l16) * HD;
        qf[0] = *(const bf16x8*)&q0[quad * 8];
        qf[1] = *(const bf16x8*)&q0[32 + quad * 8];
    }

    bf16x8 ones;
    {
        union { short8 s; bf16x8 v; } o;
        for (int j = 0; j < 8; j++) o.s[j] = 0x3F80;
        ones = o.v;
    }

    floatx4 lfr = {0.f, 0.f, 0.f, 0.f};
    floatx4 Ofr[4];
    for (int nt = 0; nt < 4; nt++)
        for (int r = 0; r < 4; r++) Ofr[nt][r] = 0.f;

    const int ntiles = qt + 1;

#define ATTN_STAGE(bufi, kt_) do { \
    const int kb_ = (kt_) * 64; \
    const unsigned short* g0 = kgB + ((size_t)(2 * wv) * S_LEN + kb_ + lane) * 8; \
    gload_lds16(g0,             &Ks[bufi][(2 * wv) * 512]); \
    gload_lds16(g0 + S_LEN * 8, &Ks[bufi][(2 * wv + 1) * 512]); \
    const unsigned short* g1 = vgB + ((size_t)((kb_ >> 3) + 2 * wv) * 64 + lane) * 8; \
    gload_lds16(g1,          &Vt[bufi][(2 * wv) * 512]); \
    gload_lds16(g1 + 64 * 8, &Vt[bufi][(2 * wv + 1) * 512]); \
} while (0)

#define ATTN_COMPUTE(bufi, kt_) do { \
    const int kbase = (kt_) * 64; \
    float pex[4][4]; \
    _Pragma("unroll") for (int sub = 0; sub < 4; sub++) { \
        bf16x8 kf0 = *(const bf16x8*)&Ks[bufi][(0 * 4 + quad) * 512 + (sub * 16 + l16) * 8]; \
        bf16x8 kf1 = *(const bf16x8*)&Ks[bufi][(1 * 4 + quad) * 512 + (sub * 16 + l16) * 8]; \
        floatx4 sacc = {0.f, 0.f, 0.f, 0.f}; \
        sacc = __builtin_amdgcn_mfma_f32_16x16x32_bf16(kf0, qf[0], sacc, 0, 0, 0); \
        sacc = __builtin_amdgcn_mfma_f32_16x16x32_bf16(kf1, qf[1], sacc, 0, 0, 0); \
        _Pragma("unroll") for (int r = 0; r < 4; r++) pex[sub][r] = sacc[r]; \
    } \
    if ((kt_) == qt) { \
        const int q = qt * 64 + wv * 16 + l16; \
        _Pragma("unroll") for (int sub = 0; sub < 4; sub++) \
            _Pragma("unroll") for (int r = 0; r < 4; r++) { \
                const int key = kbase + sub * 16 + quad * 4 + r; \
                if (key > q) pex[sub][r] = -1e30f; \
            } \
    } \
    _Pragma("unroll") for (int sub = 0; sub < 4; sub++) { \
        union { unsigned short s[4]; uint2 u; } pk; \
        _Pragma("unroll") for (int r = 0; r < 4; r++) pk.s[r] = f2bf(__expf(pex[sub][r])); \
        *(uint2*)&Pw[wv][l16 * 72 + sub * 16 + quad * 4] = pk.u; \
    } \
    { \
        bf16x8 pf0 = *(const bf16x8*)&Pw[wv][l16 * 72 + quad * 8]; \
        bf16x8 pf1 = *(const bf16x8*)&Pw[wv][l16 * 72 + 32 + quad * 8]; \
        lfr = __builtin_amdgcn_mfma_f32_16x16x32_bf16(ones, pf0, lfr, 0, 0, 0); \
        lfr = __builtin_amdgcn_mfma_f32_16x16x32_bf16(ones, pf1, lfr, 0, 0, 0); \
        _Pragma("unroll") for (int nt = 0; nt < 4; nt++) { \
            bf16x8 v0 = *(const bf16x8*)&Vt[bufi][(0 * 4 + quad) * 512 + (nt * 16 + l16) * 8]; \
            bf16x8 v1 = *(const bf16x8*)&Vt[bufi][(1 * 4 + quad) * 512 + (nt * 16 + l16) * 8]; \
            Ofr[nt] = __builtin_amdgcn_mfma_f32_16x16x32_bf16(pf0, v0, Ofr[nt], 0, 0, 0); \
            Ofr[nt] = __builtin_amdgcn_mfma_f32_16x16x32_bf16(pf1, v1, Ofr[nt], 0, 0, 0); \
        } \
    } \
} while (0)

    ATTN_STAGE(0, 0);
    __syncthreads();
    for (int kt = 0; kt < ntiles; ) {
        if (kt + 1 < ntiles) ATTN_STAGE(1, kt + 1);
        ATTN_COMPUTE(0, kt);
        kt++;
        if (kt >= ntiles) break;
        __syncthreads();
        if (kt + 1 < ntiles) ATTN_STAGE(0, kt + 1);
        ATTN_COMPUTE(1, kt);
        kt++;
        if (kt >= ntiles) break;
        __syncthreads();
    }

    float linv[4];
    #pragma unroll
    for (int r = 0; r < 4; r++) {
        float lq = __shfl(lfr[0], (lane & 48) | (quad * 4 + r), 64);
        linv[r] = 1.f / lq;
    }
    #pragma unroll
    for (int nt = 0; nt < 4; nt++)
        #pragma unroll
        for (int r = 0; r < 4; r++) {
            const int s = qt * 64 + wv * 16 + quad * 4 + r;
            ao[((size_t)b * S_LEN + s) * DMODEL + h * HD + nt * 16 + l16] =
                f2bf(Ofr[nt][r] * linv[r]);
        }
#undef ATTN_STAGE
#undef ATTN_COMPUTE
}

// ---------------------------------------------------------------------------
// K3: out = ao @ w_proj_bf16^T + b_proj.  128x64 tile, ring-4 counted-vmcnt
// pipeline (same scheme as K1; 3 loads/stage -> vmcnt 6/3/0).
// ---------------------------------------------------------------------------
#define PROJ_STAGE(bi, kk) do { \
    unsigned short* dA_ = smem + (bi) * 6144; \
    unsigned short* dB_ = dA_ + 4096; \
    gload_lds16(ag + (kk),               dA_ + wv * 512); \
    gload_lds16(ag + 64 * DMODEL + (kk), dA_ + 2048 + wv * 512); \
    gload_lds16(bg + (kk),               dB_ + wv * 512); \
} while (0)

#define PROJ_COMPUTE(bi) do { \
    const unsigned short* sA_ = smem + (bi) * 6144; \
    const unsigned short* sB_ = sA_ + 4096; \
    bf16x8 af[4]; \
    _Pragma("unroll") for (int m_ = 0; m_ < 4; m_++) af[m_] = *(const bf16x8*)&sA_[aoff[m_]]; \
    _Pragma("unroll") for (int n_ = 0; n_ < 2; n_++) { \
        bf16x8 bf = *(const bf16x8*)&sB_[boff[n_]]; \
        _Pragma("unroll") for (int m_ = 0; m_ < 4; m_++) \
            acc[m_][n_] = __builtin_amdgcn_mfma_f32_16x16x32_bf16(af[m_], bf, acc[m_][n_], 0, 0, 0); \
    } \
} while (0)

__global__ __launch_bounds__(256, 3) void proj_kernel(
    const unsigned short* __restrict__ a, const unsigned short* __restrict__ wpb,
    const float* __restrict__ bias, float* __restrict__ out)
{
    // ring-4: buffer i at smem + i*6144 (A 4096 shorts, B 2048 shorts) = 48KB
    __shared__ __align__(16) unsigned short smem[24576];

    const int t = threadIdx.x;
    const int v = (blockIdx.x & 7) * 64 + (blockIdx.x >> 3);
    const int mbase = (v >> 4) * 128;
    const int nbase = (v & 15) * 64;
    const int wv = t >> 6, lane = t & 63, quad = lane >> 4, l16 = lane & 15;
    const int wr = wv >> 1, wc = wv & 1;

    floatx4 acc[4][2];
    #pragma unroll
    for (int m = 0; m < 4; m++)
        #pragma unroll
        for (int n = 0; n < 2; n++)
            #pragma unroll
            for (int r = 0; r < 4; r++) acc[m][n][r] = 0.f;

    const int srow = t >> 2;
    const int schunk = (t & 3) ^ SROW(srow);
    const unsigned short* ag = a + (size_t)(mbase + srow) * DMODEL + schunk * 8;
    const unsigned short* bg = wpb + (size_t)(nbase + srow) * DMODEL + schunk * 8;

    const int Sl = SROW(l16);
    int aoff[4], boff[2];
    #pragma unroll
    for (int m = 0; m < 4; m++) aoff[m] = (wr * 64 + m * 16 + l16) * 32 + (quad ^ Sl) * 8;
    #pragma unroll
    for (int n = 0; n < 2; n++) boff[n] = (wc * 32 + n * 16 + l16) * 32 + (quad ^ Sl) * 8;

    PROJ_STAGE(0, 0);
    PROJ_STAGE(1, 32);
    #pragma unroll 4
    for (int tt = 0; tt < 28; tt++) {
        PROJ_STAGE((tt + 2) & 3, (tt + 2) * 32);
        WAITV_BAR(6);
        PROJ_COMPUTE(tt & 3);
    }
    PROJ_STAGE(2, 30 * 32); WAITV_BAR(6); PROJ_COMPUTE(0);
    PROJ_STAGE(3, 31 * 32); WAITV_BAR(6); PROJ_COMPUTE(1);
    WAITV_BAR(3); PROJ_COMPUTE(2);
    WAITV_BAR(0); PROJ_COMPUTE(3);

    #pragma unroll
    for (int n = 0; n < 2; n++) {
        const int nn = nbase + wc * 32 + n * 16 + l16;
        const float bvv = bias[nn];
        #pragma unroll
        for (int m = 0; m < 4; m++)
            #pragma unroll
            for (int r = 0; r < 4; r++)
                out[(size_t)(mbase + wr * 64 + m * 16 + quad * 4 + r) * DMODEL + nn] =
                    acc[m][n][r] + bvv;
    }
}

extern "C" void kernel_launch(void* const* d_in, const int* in_sizes, int n_in,
                              void* d_out, int out_size, void* d_ws, size_t ws_size,
                              hipStream_t stream) {
    const float* x      = (const float*)d_in[0];
    const float* freqs  = (const float*)d_in[2];
    const float* w_qkv  = (const float*)d_in[3];
    const float* b_qkv  = (const float*)d_in[4];
    const float* w_proj = (const float*)d_in[5];
    const float* b_proj = (const float*)d_in[6];
    float* out = (float*)d_out;

    unsigned short* ws = (unsigned short*)d_ws;
    const size_t HSZ = (size_t)2 * NH * S_LEN * HD;   // 4,194,304 shorts
    unsigned short* qb  = ws;
    unsigned short* kb  = ws + HSZ;
    unsigned short* vb  = ws + 2 * HSZ;
    unsigned short* ao  = ws + 3 * HSZ;
    unsigned short* xb  = ws + 4 * HSZ;                       // 4096x1024 bf16
    unsigned short* wqb = xb + (size_t)4096 * 1024;           // 3072x1024 bf16
    unsigned short* wpb = wqb + (size_t)3072 * 1024;          // 1024x1024 bf16
    float2* cs = (float2*)(wpb + (size_t)1024 * 1024);        // 2048x32 (cos,sin)

    prep_kernel<<<2048, 256, 0, stream>>>(x, w_qkv, w_proj, freqs, xb, wqb, wpb, cs);
    qkv_gemm_kernel<<<768, 256, 0, stream>>>(xb, wqb, b_qkv, cs, qb, kb, vb);
    attn_kernel<<<1024, 256, 0, stream>>>(qb, kb, vb, ao);
    proj_kernel<<<512, 256, 0, stream>>>(ao, wpb, b_proj, out);
}

// Round 5
// 195.484 us; speedup vs baseline: 1.0146x; 1.0146x over previous
//
#include <hip/hip_runtime.h>

// Problem constants: B=2, S=2048, D=1024, H=16, HD=64
#define S_LEN 2048
#define NH 16
#define HD 64
#define DMODEL 1024

typedef __bf16 bf16x8 __attribute__((ext_vector_type(8)));
typedef float floatx4 __attribute__((ext_vector_type(4)));
typedef short short8 __attribute__((ext_vector_type(8)));

__device__ inline unsigned short f2bf(float f) {
    union { float f; unsigned u; } v; v.f = f;
    unsigned u = v.u;
    unsigned r = (u + 0x7FFFu + ((u >> 16) & 1u)) >> 16;  // RNE
    return (unsigned short)r;
}

__device__ __forceinline__ void gload_lds16(const void* g, void* l) {
    __builtin_amdgcn_global_load_lds(
        (const __attribute__((address_space(1))) unsigned int*)g,
        (__attribute__((address_space(3))) unsigned int*)l, 16, 0, 0);
}

// counted-vmcnt barrier: each wave waits for its own oldest loads BEFORE the
// barrier, so after the barrier ALL waves' loads for that tile have landed.
// Newer loads (up to N) stay in flight ACROSS the barrier (T4).
#define WAITV_BAR(N) do { \
    asm volatile("s_waitcnt vmcnt(" #N ")\n\ts_barrier" ::: "memory"); \
    __builtin_amdgcn_sched_barrier(0); \
} while (0)

// ---------------------------------------------------------------------------
// K0: prepass. fp32 -> bf16 for x, w_qkv, w_proj (RNE), and cos/sin table.
// ---------------------------------------------------------------------------
__device__ __forceinline__ void cvt4(const float4* __restrict__ src,
                                     uint2* __restrict__ dst, int i) {
    float4 v = src[i];
    union { unsigned short u[4]; uint2 d; } o;
    o.u[0] = f2bf(v.x); o.u[1] = f2bf(v.y); o.u[2] = f2bf(v.z); o.u[3] = f2bf(v.w);
    dst[i] = o.d;
}

__global__ __launch_bounds__(256) void prep_kernel(
    const float* __restrict__ x, const float* __restrict__ wq,
    const float* __restrict__ wp, const float* __restrict__ freqs,
    unsigned short* __restrict__ xb, unsigned short* __restrict__ wqb,
    unsigned short* __restrict__ wpb, float2* __restrict__ cs)
{
    const int tid = blockIdx.x * 256 + threadIdx.x;
    const int nth = gridDim.x * 256;
    for (int i = tid; i < (4096 * 1024) / 4; i += nth) cvt4((const float4*)x, (uint2*)xb, i);
    for (int i = tid; i < (3072 * 1024) / 4; i += nth) cvt4((const float4*)wq, (uint2*)wqb, i);
    for (int i = tid; i < (1024 * 1024) / 4; i += nth) cvt4((const float4*)wp, (uint2*)wpb, i);
    for (int i = tid; i < S_LEN * 32; i += nth) {
        const float f = freqs[i];
        float2 c; c.x = cosf(f); c.y = sinf(f);
        cs[i] = c;
    }
}

// Bank swizzle for 32-col (4x16B-chunk) row-major LDS tiles.
#define SROW(r) (((r) & 3) ^ (((r) >> 2) & 3))

// ---------------------------------------------------------------------------
// K1: qkv = x_bf16 @ w_qkv_bf16^T + b_qkv, fused RoPE (table) + scatter.
// 128x128 tile, BK=32. RING-3 counted-vmcnt pipeline: depth-2 prefetch,
// STAGE issued AFTER the barrier (so slot reuse is barrier-separated ->
// 3 buffers suffice), vmcnt(4) per step (never drained to 0 mid-loop).
// 48KB LDS -> 3 blocks/CU -> full 768-block grid co-resident (L2 reuse).
//  q -> [bh][s][hd] row-major, PRE-SCALED by 1/sqrt(HD)=0.125 (exact)
//  k -> blocked [bh][hdblk(8)][s(2048)][8]   (RoPE applied)
//  v -> blocked [bh][sblk(256)][hd(64)][8]   (transposed via LDS tile)
// ---------------------------------------------------------------------------
#define QKV_STAGE(bi, kk) do { \
    unsigned short* dA_ = smem + (bi) * 8192; \
    unsigned short* dB_ = dA_ + 4096; \
    gload_lds16(ag + (kk),               dA_ + wv * 512); \
    gload_lds16(ag + 64 * DMODEL + (kk), dA_ + 2048 + wv * 512); \
    gload_lds16(bg + (kk),               dB_ + wv * 512); \
    gload_lds16(bg + 64 * DMODEL + (kk), dB_ + 2048 + wv * 512); \
} while (0)

#define QKV_COMPUTE(bi) do { \
    const unsigned short* sA_ = smem + (bi) * 8192; \
    const unsigned short* sB_ = sA_ + 4096; \
    bf16x8 af[4]; \
    _Pragma("unroll") for (int m_ = 0; m_ < 4; m_++) af[m_] = *(const bf16x8*)&sA_[aoff[m_]]; \
    _Pragma("unroll") for (int n_ = 0; n_ < 4; n_++) { \
        bf16x8 bf = *(const bf16x8*)&sB_[boff[n_]]; \
        _Pragma("unroll") for (int m_ = 0; m_ < 4; m_++) \
            acc[m_][n_] = __builtin_amdgcn_mfma_f32_16x16x32_bf16(af[m_], bf, acc[m_][n_], 0, 0, 0); \
    } \
} while (0)

__global__ __launch_bounds__(256, 3) void qkv_gemm_kernel(
    const unsigned short* __restrict__ xb, const unsigned short* __restrict__ wqb,
    const float* __restrict__ bias, const float2* __restrict__ cs,
    unsigned short* __restrict__ qb, unsigned short* __restrict__ kb,
    unsigned short* __restrict__ vb)
{
    // ring-3: slot i at smem + i*8192 (A 4096 shorts, B 4096 shorts) = 48KB.
    // V epilogue reuses smem as 128x72 tile (9216 shorts).
    __shared__ __align__(16) unsigned short smem[24576];

    const int t = threadIdx.x;
    const int v = (blockIdx.x & 7) * 96 + (blockIdx.x >> 3);   // XCD swizzle
    const int mbase = (v / 24) * 128;   // 32 m-tiles
    const int nbase = (v % 24) * 128;   // 24 n-tiles
    const int wv = t >> 6, lane = t & 63;
    const int quad = lane >> 4, l16 = lane & 15;
    const int wr = wv >> 1, wc = wv & 1;

    floatx4 acc[4][4];
    #pragma unroll
    for (int m = 0; m < 4; m++)
        #pragma unroll
        for (int n = 0; n < 4; n++)
            #pragma unroll
            for (int r = 0; r < 4; r++) acc[m][n][r] = 0.f;

    const int srow = t >> 2;
    const int schunk = (t & 3) ^ SROW(srow);
    const unsigned short* ag = xb + (size_t)(mbase + srow) * DMODEL + schunk * 8;
    const unsigned short* bg = wqb + (size_t)(nbase + srow) * DMODEL + schunk * 8;

    const int Sl = SROW(l16);
    int aoff[4], boff[4];
    #pragma unroll
    for (int m = 0; m < 4; m++) aoff[m] = (wr * 64 + m * 16 + l16) * 32 + (quad ^ Sl) * 8;
    #pragma unroll
    for (int n = 0; n < 4; n++) boff[n] = (wc * 64 + n * 16 + l16) * 32 + (quad ^ Sl) * 8;

    // Ring-3 schedule. Invariant at iter t's WAITV_BAR: tiles {t, t+1} in
    // flight (8 loads); vmcnt(4) -> tile t landed for THIS wave; barrier ->
    // landed for ALL waves, and all waves finished COMPUTE(t-1) (which read
    // slot (t-1)%3 == (t+2)%3) -> safe to restage that slot.
    QKV_STAGE(0, 0);
    QKV_STAGE(1, 32);
    for (int tb = 0; tb < 30; tb += 3) {
        WAITV_BAR(4); QKV_STAGE(2, (tb + 2) * 32); QKV_COMPUTE(0);
        WAITV_BAR(4); QKV_STAGE(0, (tb + 3) * 32); QKV_COMPUTE(1);
        WAITV_BAR(4); QKV_STAGE(1, (tb + 4) * 32); QKV_COMPUTE(2);
    }
    WAITV_BAR(4); QKV_COMPUTE(0);    // tile 30
    WAITV_BAR(0); QKV_COMPUTE(1);    // tile 31

    const int part = nbase >> 10;                 // 0=q 1=k 2=v
    const int bidx = mbase >> 11;
    const int s0   = mbase & 2047;

    if (part == 2) {
        unsigned short* Vt = smem;                // 128 hd x 72 s-pad
        const int hb = (nbase & 1023) >> 6;
        float bvv[4];
        #pragma unroll
        for (int nt = 0; nt < 4; nt++) bvv[nt] = bias[nbase + wc * 64 + nt * 16 + l16];
        #pragma unroll
        for (int shalf = 0; shalf < 2; shalf++) {
            __syncthreads();
            if (wr == shalf) {
                #pragma unroll
                for (int nt = 0; nt < 4; nt++) {
                    const int hdl = wc * 64 + nt * 16 + l16;
                    #pragma unroll
                    for (int m = 0; m < 4; m++)
                        #pragma unroll
                        for (int r = 0; r < 4; r++)
                            Vt[hdl * 72 + m * 16 + quad * 4 + r] = f2bf(acc[m][nt][r] + bvv[nt]);
                }
            }
            __syncthreads();
            const int hdl = t & 127, sp = t >> 7;
            const size_t bh2 = (size_t)bidx * NH + hb + (hdl >> 6);
            #pragma unroll
            for (int c = 0; c < 4; c++) {
                const int sl0 = (sp * 4 + c) * 8;
                const int sg = s0 + shalf * 64 + sl0;
                short8 vv = *(const short8*)&Vt[hdl * 72 + sl0];
                *(short8*)&vb[((bh2 * 256 + (sg >> 3)) * 64 + (hdl & 63)) * 8] = vv;
            }
        }
    } else {
        const size_t bhb = (size_t)bidx * NH;
        const int odd = l16 & 1;
        #pragma unroll
        for (int nt = 0; nt < 4; nt++) {
            const int n_ = nbase + wc * 64 + nt * 16 + l16;
            const int hd = n_ & 63;
            const size_t bh = bhb + ((n_ & 1023) >> 6);
            const float bvv = bias[n_];
            const int ci = (nt * 16 + l16) >> 1;
            #pragma unroll
            for (int m = 0; m < 4; m++) {
                #pragma unroll
                for (int r = 0; r < 4; r++) {
                    const int s = s0 + wr * 64 + m * 16 + quad * 4 + r;
                    float val = acc[m][nt][r] + bvv;
                    float other = __shfl_xor(val, 1, 64);
                    const float2 csv = cs[(size_t)s * 32 + ci];
                    float outv = odd ? fmaf(other, csv.y, val * csv.x)
                                     : fmaf(-other, csv.y, val * csv.x);
                    if (part == 0) {
                        qb[(bh * S_LEN + s) * HD + hd] = f2bf(outv * 0.125f);
                    } else {
                        kb[((bh * 8 + (hd >> 3)) * (size_t)S_LEN + s) * 8 + (hd & 7)] = f2bf(outv);
                    }
                }
            }
        }
    }
}

// ---------------------------------------------------------------------------
// K2: causal flash attention (unchanged from R3: 2-phase dbuf staging,
// reversed qt launch order).
// ---------------------------------------------------------------------------
__global__ __launch_bounds__(256, 3) void attn_kernel(
    const unsigned short* __restrict__ qb, const unsigned short* __restrict__ kb,
    const unsigned short* __restrict__ vbk, unsigned short* __restrict__ ao)
{
    __shared__ __align__(16) unsigned short Ks[2][8 * 512];
    __shared__ __align__(16) unsigned short Vt[2][8 * 512];
    __shared__ __align__(16) unsigned short Pw[4][16 * 72];

    const int t = threadIdx.x;
    const int wv = t >> 6, lane = t & 63, quad = lane >> 4, l16 = lane & 15;
    const int qt   = 31 - (blockIdx.x >> 5);      // reversed: long blocks first
    const int bhid = blockIdx.x & 31;
    const int h = bhid & 15, b = bhid >> 4;
    const size_t bh = (size_t)b * NH + h;
    const unsigned short* qg  = qb + bh * S_LEN * HD;
    const unsigned short* kgB = kb + bh * 8 * S_LEN * 8;
    const unsigned short* vgB = vbk + bh * 256 * 64 * 8;

    bf16x8 qf[2];
    {
        const unsigned short* q0 = qg + (size_t)(qt * 64 + wv * 16 + l16) * HD;
        qf[0] = *(const bf16x8*)&q0[quad * 8];
        qf[1] = *(const bf16x8*)&q0[32 + quad * 8];
    }

    bf16x8 ones;
    {
        union { short8 s; bf16x8 v; } o;
        for (int j = 0; j < 8; j++) o.s[j] = 0x3F80;
        ones = o.v;
    }

    floatx4 lfr = {0.f, 0.f, 0.f, 0.f};
    floatx4 Ofr[4];
    for (int nt = 0; nt < 4; nt++)
        for (int r = 0; r < 4; r++) Ofr[nt][r] = 0.f;

    const int ntiles = qt + 1;

#define ATTN_STAGE(bufi, kt_) do { \
    const int kb_ = (kt_) * 64; \
    const unsigned short* g0 = kgB + ((size_t)(2 * wv) * S_LEN + kb_ + lane) * 8; \
    gload_lds16(g0,             &Ks[bufi][(2 * wv) * 512]); \
    gload_lds16(g0 + S_LEN * 8, &Ks[bufi][(2 * wv + 1) * 512]); \
    const unsigned short* g1 = vgB + ((size_t)((kb_ >> 3) + 2 * wv) * 64 + lane) * 8; \
    gload_lds16(g1,          &Vt[bufi][(2 * wv) * 512]); \
    gload_lds16(g1 + 64 * 8, &Vt[bufi][(2 * wv + 1) * 512]); \
} while (0)

#define ATTN_COMPUTE(bufi, kt_) do { \
    const int kbase = (kt_) * 64; \
    float pex[4][4]; \
    _Pragma("unroll") for (int sub = 0; sub < 4; sub++) { \
        bf16x8 kf0 = *(const bf16x8*)&Ks[bufi][(0 * 4 + quad) * 512 + (sub * 16 + l16) * 8]; \
        bf16x8 kf1 = *(const bf16x8*)&Ks[bufi][(1 * 4 + quad) * 512 + (sub * 16 + l16) * 8]; \
        floatx4 sacc = {0.f, 0.f, 0.f, 0.f}; \
        sacc = __builtin_amdgcn_mfma_f32_16x16x32_bf16(kf0, qf[0], sacc, 0, 0, 0); \
        sacc = __builtin_amdgcn_mfma_f32_16x16x32_bf16(kf1, qf[1], sacc, 0, 0, 0); \
        _Pragma("unroll") for (int r = 0; r < 4; r++) pex[sub][r] = sacc[r]; \
    } \
    if ((kt_) == qt) { \
        const int q = qt * 64 + wv * 16 + l16; \
        _Pragma("unroll") for (int sub = 0; sub < 4; sub++) \
            _Pragma("unroll") for (int r = 0; r < 4; r++) { \
                const int key = kbase + sub * 16 + quad * 4 + r; \
                if (key > q) pex[sub][r] = -1e30f; \
            } \
    } \
    _Pragma("unroll") for (int sub = 0; sub < 4; sub++) { \
        union { unsigned short s[4]; uint2 u; } pk; \
        _Pragma("unroll") for (int r = 0; r < 4; r++) pk.s[r] = f2bf(__expf(pex[sub][r])); \
        *(uint2*)&Pw[wv][l16 * 72 + sub * 16 + quad * 4] = pk.u; \
    } \
    { \
        bf16x8 pf0 = *(const bf16x8*)&Pw[wv][l16 * 72 + quad * 8]; \
        bf16x8 pf1 = *(const bf16x8*)&Pw[wv][l16 * 72 + 32 + quad * 8]; \
        lfr = __builtin_amdgcn_mfma_f32_16x16x32_bf16(ones, pf0, lfr, 0, 0, 0); \
        lfr = __builtin_amdgcn_mfma_f32_16x16x32_bf16(ones, pf1, lfr, 0, 0, 0); \
        _Pragma("unroll") for (int nt = 0; nt < 4; nt++) { \
            bf16x8 v0 = *(const bf16x8*)&Vt[bufi][(0 * 4 + quad) * 512 + (nt * 16 + l16) * 8]; \
            bf16x8 v1 = *(const bf16x8*)&Vt[bufi][(1 * 4 + quad) * 512 + (nt * 16 + l16) * 8]; \
            Ofr[nt] = __builtin_amdgcn_mfma_f32_16x16x32_bf16(pf0, v0, Ofr[nt], 0, 0, 0); \
            Ofr[nt] = __builtin_amdgcn_mfma_f32_16x16x32_bf16(pf1, v1, Ofr[nt], 0, 0, 0); \
        } \
    } \
} while (0)

    ATTN_STAGE(0, 0);
    __syncthreads();
    for (int kt = 0; kt < ntiles; ) {
        if (kt + 1 < ntiles) ATTN_STAGE(1, kt + 1);
        ATTN_COMPUTE(0, kt);
        kt++;
        if (kt >= ntiles) break;
        __syncthreads();
        if (kt + 1 < ntiles) ATTN_STAGE(0, kt + 1);
        ATTN_COMPUTE(1, kt);
        kt++;
        if (kt >= ntiles) break;
        __syncthreads();
    }

    float linv[4];
    #pragma unroll
    for (int r = 0; r < 4; r++) {
        float lq = __shfl(lfr[0], (lane & 48) | (quad * 4 + r), 64);
        linv[r] = 1.f / lq;
    }
    #pragma unroll
    for (int nt = 0; nt < 4; nt++)
        #pragma unroll
        for (int r = 0; r < 4; r++) {
            const int s = qt * 64 + wv * 16 + quad * 4 + r;
            ao[((size_t)b * S_LEN + s) * DMODEL + h * HD + nt * 16 + l16] =
                f2bf(Ofr[nt][r] * linv[r]);
        }
#undef ATTN_STAGE
#undef ATTN_COMPUTE
}

// ---------------------------------------------------------------------------
// K3: out = ao @ w_proj_bf16^T + b_proj.  128x64 tile, RING-3 counted-vmcnt
// pipeline (same scheme as K1; 3 loads/stage -> vmcnt(3), tail 3/0).
// 36KB LDS.
// ---------------------------------------------------------------------------
#define PROJ_STAGE(bi, kk) do { \
    unsigned short* dA_ = smem + (bi) * 6144; \
    unsigned short* dB_ = dA_ + 4096; \
    gload_lds16(ag + (kk),               dA_ + wv * 512); \
    gload_lds16(ag + 64 * DMODEL + (kk), dA_ + 2048 + wv * 512); \
    gload_lds16(bg + (kk),               dB_ + wv * 512); \
} while (0)

#define PROJ_COMPUTE(bi) do { \
    const unsigned short* sA_ = smem + (bi) * 6144; \
    const unsigned short* sB_ = sA_ + 4096; \
    bf16x8 af[4]; \
    _Pragma("unroll") for (int m_ = 0; m_ < 4; m_++) af[m_] = *(const bf16x8*)&sA_[aoff[m_]]; \
    _Pragma("unroll") for (int n_ = 0; n_ < 2; n_++) { \
        bf16x8 bf = *(const bf16x8*)&sB_[boff[n_]]; \
        _Pragma("unroll") for (int m_ = 0; m_ < 4; m_++) \
            acc[m_][n_] = __builtin_amdgcn_mfma_f32_16x16x32_bf16(af[m_], bf, acc[m_][n_], 0, 0, 0); \
    } \
} while (0)

__global__ __launch_bounds__(256, 3) void proj_kernel(
    const unsigned short* __restrict__ a, const unsigned short* __restrict__ wpb,
    const float* __restrict__ bias, float* __restrict__ out)
{
    // ring-3: slot i at smem + i*6144 (A 4096 shorts, B 2048 shorts) = 36KB
    __shared__ __align__(16) unsigned short smem[18432];

    const int t = threadIdx.x;
    const int v = (blockIdx.x & 7) * 64 + (blockIdx.x >> 3);
    const int mbase = (v >> 4) * 128;
    const int nbase = (v & 15) * 64;
    const int wv = t >> 6, lane = t & 63, quad = lane >> 4, l16 = lane & 15;
    const int wr = wv >> 1, wc = wv & 1;

    floatx4 acc[4][2];
    #pragma unroll
    for (int m = 0; m < 4; m++)
        #pragma unroll
        for (int n = 0; n < 2; n++)
            #pragma unroll
            for (int r = 0; r < 4; r++) acc[m][n][r] = 0.f;

    const int srow = t >> 2;
    const int schunk = (t & 3) ^ SROW(srow);
    const unsigned short* ag = a + (size_t)(mbase + srow) * DMODEL + schunk * 8;
    const unsigned short* bg = wpb + (size_t)(nbase + srow) * DMODEL + schunk * 8;

    const int Sl = SROW(l16);
    int aoff[4], boff[2];
    #pragma unroll
    for (int m = 0; m < 4; m++) aoff[m] = (wr * 64 + m * 16 + l16) * 32 + (quad ^ Sl) * 8;
    #pragma unroll
    for (int n = 0; n < 2; n++) boff[n] = (wc * 32 + n * 16 + l16) * 32 + (quad ^ Sl) * 8;

    PROJ_STAGE(0, 0);
    PROJ_STAGE(1, 32);
    for (int tb = 0; tb < 30; tb += 3) {
        WAITV_BAR(3); PROJ_STAGE(2, (tb + 2) * 32); PROJ_COMPUTE(0);
        WAITV_BAR(3); PROJ_STAGE(0, (tb + 3) * 32); PROJ_COMPUTE(1);
        WAITV_BAR(3); PROJ_STAGE(1, (tb + 4) * 32); PROJ_COMPUTE(2);
    }
    WAITV_BAR(3); PROJ_COMPUTE(0);   // tile 30
    WAITV_BAR(0); PROJ_COMPUTE(1);   // tile 31

    #pragma unroll
    for (int n = 0; n < 2; n++) {
        const int nn = nbase + wc * 32 + n * 16 + l16;
        const float bvv = bias[nn];
        #pragma unroll
        for (int m = 0; m < 4; m++)
            #pragma unroll
            for (int r = 0; r < 4; r++)
                out[(size_t)(mbase + wr * 64 + m * 16 + quad * 4 + r) * DMODEL + nn] =
                    acc[m][n][r] + bvv;
    }
}

extern "C" void kernel_launch(void* const* d_in, const int* in_sizes, int n_in,
                              void* d_out, int out_size, void* d_ws, size_t ws_size,
                              hipStream_t stream) {
    const float* x      = (const float*)d_in[0];
    const float* freqs  = (const float*)d_in[2];
    const float* w_qkv  = (const float*)d_in[3];
    const float* b_qkv  = (const float*)d_in[4];
    const float* w_proj = (const float*)d_in[5];
    const float* b_proj = (const float*)d_in[6];
    float* out = (float*)d_out;

    unsigned short* ws = (unsigned short*)d_ws;
    const size_t HSZ = (size_t)2 * NH * S_LEN * HD;   // 4,194,304 shorts
    unsigned short* qb  = ws;
    unsigned short* kb  = ws + HSZ;
    unsigned short* vb  = ws + 2 * HSZ;
    unsigned short* ao  = ws + 3 * HSZ;
    unsigned short* xb  = ws + 4 * HSZ;                       // 4096x1024 bf16
    unsigned short* wqb = xb + (size_t)4096 * 1024;           // 3072x1024 bf16
    unsigned short* wpb = wqb + (size_t)3072 * 1024;          // 1024x1024 bf16
    float2* cs = (float2*)(wpb + (size_t)1024 * 1024);        // 2048x32 (cos,sin)

    prep_kernel<<<2048, 256, 0, stream>>>(x, w_qkv, w_proj, freqs, xb, wqb, wpb, cs);
    qkv_gemm_kernel<<<768, 256, 0, stream>>>(xb, wqb, b_qkv, cs, qb, kb, vb);
    attn_kernel<<<1024, 256, 0, stream>>>(qb, kb, vb, ao);
    proj_kernel<<<512, 256, 0, stream>>>(ao, wpb, b_proj, out);
}